// Round 14
// baseline (373.081 us; speedup 1.0000x reference)
//
#include <hip/hip_runtime.h>
#include <hip/hip_bf16.h>
#include <hip/hip_fp16.h>
#include <math.h>

#define N_NODES 50000
#define E_EDGES 800000
#define NEG_SLOPE 0.2f
#define EPS 1e-16f
#define NB_SCAN ((N_NODES + 255) / 256)   // 196
#define GX1 ((N_NODES + 127) / 128)       // 391

typedef _Float16 f16x8 __attribute__((ext_vector_type(8)));
typedef _Float16 h2f   __attribute__((ext_vector_type(2)));
typedef float    f32x4 __attribute__((ext_vector_type(4)));

// fp32 dot-accumulate of an fp16 pair product: v_dot2_f32_f16 where available
__device__ __forceinline__ float dot2acc(h2f a, h2f b, float c) {
#if __has_builtin(__builtin_amdgcn_fdot2)
    return __builtin_amdgcn_fdot2(a, b, c, false);
#else
    return c + (float)a[0] * (float)b[0] + (float)a[1] * (float)b[1];
#endif
}

// packed leaky-relu: max(s, 0.2*s) elementwise (v_pk_mul + v_pk_max)
__device__ __forceinline__ h2f leaky2(h2f s) {
    h2f t = s * (_Float16)NEG_SLOPE;
    return __builtin_elementwise_max(s, t);
}

__device__ __forceinline__ h2f cvt_h2(float x, float y) {
    h2f r; r[0] = (_Float16)x; r[1] = (_Float16)y; return r;
}

// load 8 contiguous elements as f16x8, converting if input is fp32
__device__ __forceinline__ f16x8 load8(const float* p) {
    const float4 v0 = *(const float4*)p;
    const float4 v1 = *(const float4*)(p + 4);
    f16x8 r;
    r[0] = (_Float16)v0.x; r[1] = (_Float16)v0.y;
    r[2] = (_Float16)v0.z; r[3] = (_Float16)v0.w;
    r[4] = (_Float16)v1.x; r[5] = (_Float16)v1.y;
    r[6] = (_Float16)v1.z; r[7] = (_Float16)v1.w;
    return r;
}
__device__ __forceinline__ f16x8 load8(const _Float16* p) {
    return *(const f16x8*)p;
}

// ---------------------------------------------------------------------------
// MFMA GEMM (fp16 compute, fp32 accum): Y[N, M2] = X[N,K] @ Wt[M2,K]^T,
// fp16 output. X fp32 (converted during staging) or fp16, templated.
// 128x256 tile, BK=32 (R11 best), 4 waves (2x2 over 64x128), 4x8 MFMA/wave.
// ---------------------------------------------------------------------------
template <typename IT>
__global__ __launch_bounds__(256, 2)
void gemm_mfma(const IT* __restrict__ X, const __half* __restrict__ Wth,
               __half* __restrict__ Y, int Nrows, int K, int M2)
{
    const _Float16* Wt = (const _Float16*)Wth;
    __shared__ _Float16 As[128][40];
    __shared__ _Float16 Bs[256][40];
    const int tid  = threadIdx.x;
    const int row0 = blockIdx.x * 128;
    const int col0 = blockIdx.y * 256;
    const int lane = tid & 63;
    const int wv   = tid >> 6;
    const int wr   = (wv >> 1) * 64;
    const int wc   = (wv & 1) * 128;
    const int fm   = lane & 15;
    const int fk   = (lane >> 4) * 8;
    const int quad = lane >> 4;

    f32x4 acc[4][8] = {};

    for (int k0 = 0; k0 < K; k0 += 32) {
        #pragma unroll
        for (int p = 0; p < 2; ++p) {
            const int idx = tid + p * 256;
            const int r = idx >> 2;
            const int c = (idx & 3) * 8;
            const int gr = row0 + r;
            f16x8 v = {};
            if (gr < Nrows)
                v = load8(X + (size_t)gr * K + k0 + c);
            *(f16x8*)&As[r][c] = v;
        }
        #pragma unroll
        for (int p = 0; p < 4; ++p) {
            const int idx = tid + p * 256;
            const int r = idx >> 2;
            const int c = (idx & 3) * 8;
            *(f16x8*)&Bs[r][c] = *(const f16x8*)(Wt + (size_t)(col0 + r) * K + k0 + c);
        }
        __syncthreads();

        f16x8 bf[8];
        #pragma unroll
        for (int j = 0; j < 8; ++j)
            bf[j] = *(const f16x8*)&Bs[wc + j * 16 + fm][fk];
        #pragma unroll
        for (int i = 0; i < 4; ++i) {
            const f16x8 af = *(const f16x8*)&As[wr + i * 16 + fm][fk];
            #pragma unroll
            for (int j = 0; j < 8; ++j)
                acc[i][j] = __builtin_amdgcn_mfma_f32_16x16x32_f16(af, bf[j], acc[i][j], 0, 0, 0);
        }
        __syncthreads();
    }

    #pragma unroll
    for (int i = 0; i < 4; ++i) {
        #pragma unroll
        for (int j = 0; j < 8; ++j) {
            const int col = col0 + wc + j * 16 + fm;
            #pragma unroll
            for (int rg = 0; rg < 4; ++rg) {
                const int row = row0 + wr + i * 16 + quad * 4 + rg;
                if (row < Nrows)
                    Y[(size_t)row * M2 + col] = __float2half(acc[i][j][rg]);
            }
        }
    }
}

// ---------------------------------------------------------------------------
// Fused: weight-pair fp16 transpose convert (blocks 0..511) + dst histogram
// (remaining blocks). deg must be zeroed beforehand (same-stream memset).
// ---------------------------------------------------------------------------
#define CVT_BLOCKS 512   // (512*128 + 256*256) / 256
__global__ __launch_bounds__(256)
void cvt_and_hist(const float* __restrict__ Wl1, const float* __restrict__ Wr1,
                  const float* __restrict__ Wl2, const float* __restrict__ Wr2,
                  __half* __restrict__ W1t, __half* __restrict__ W2t,
                  const int* __restrict__ dst, int* __restrict__ deg)
{
    const int b = blockIdx.x;
    if (b < CVT_BLOCKS) {
        int id = b * 256 + threadIdx.x;
        if (id < 512 * 128) {
            const int n = id >> 7, k = id & 127;          // K=128, M=256
            const float* W = (n < 256) ? Wl1 : Wr1;
            const int nn = (n < 256) ? n : n - 256;
            W1t[id] = __float2half(W[(size_t)k * 256 + nn]);
        } else {
            id -= 512 * 128;
            const int n = id >> 8, k = id & 255;          // K=256, M=128
            const float* W = (n < 128) ? Wl2 : Wr2;
            const int nn = (n < 128) ? n : n - 128;
            W2t[id] = __float2half(W[(size_t)k * 128 + nn]);
        }
    } else {
        const int i = (b - CVT_BLOCKS) * 256 + threadIdx.x;
        if (i < E_EDGES) atomicAdd(&deg[dst[i]], 1);
    }
}

// ---------------------------------------------------------------------------
// Single-pass exclusive scan of deg -> rowptr/cursor, decoupled lookback.
// Ticket-ordered blocks; state[bid] packs flag(hi32:1=partial,2=inclusive) |
// sum(lo32), agent-scope acq/rel. 196 blocks are co-resident -> spin safe.
// state + ticket zeroed by the deg memset.
// ---------------------------------------------------------------------------
__global__ __launch_bounds__(256)
void scan_onepass(const int* __restrict__ deg, unsigned long long* __restrict__ state,
                  int* __restrict__ ticket, int* __restrict__ rowptr,
                  int* __restrict__ cursor)
{
    __shared__ int s_bid;
    __shared__ int ws[4];
    __shared__ int s_run;
    if (threadIdx.x == 0) s_bid = atomicAdd(ticket, 1);
    __syncthreads();
    const int bid = s_bid;
    const int i = bid * 256 + threadIdx.x;
    const int lane = threadIdx.x & 63;
    const int wid = threadIdx.x >> 6;
    const int val = (i < N_NODES) ? deg[i] : 0;

    int v = val;
    #pragma unroll
    for (int off = 1; off < 64; off <<= 1) {
        int t = __shfl_up(v, off, 64);
        if (lane >= off) v += t;
    }
    if (lane == 63) ws[wid] = v;
    __syncthreads();
    int woff = 0;
    for (int k = 0; k < wid; ++k) woff += ws[k];
    const int locincl = woff + v;
    const int total = ws[0] + ws[1] + ws[2] + ws[3];

    if (threadIdx.x == 0) {
        const unsigned long long fl = (bid == 0) ? 2ULL : 1ULL;
        __hip_atomic_store(&state[bid], (fl << 32) | (unsigned)total,
                           __ATOMIC_RELEASE, __HIP_MEMORY_SCOPE_AGENT);
        int run = 0;
        if (bid > 0) {
            int t = bid - 1;
            while (true) {
                const unsigned long long st =
                    __hip_atomic_load(&state[t], __ATOMIC_ACQUIRE, __HIP_MEMORY_SCOPE_AGENT);
                const unsigned fl2 = (unsigned)(st >> 32);
                if (fl2 == 2u) { run += (int)(unsigned)st; break; }
                if (fl2 == 1u) { run += (int)(unsigned)st; --t; }
            }
            __hip_atomic_store(&state[bid], (2ULL << 32) | (unsigned)(run + total),
                               __ATOMIC_RELEASE, __HIP_MEMORY_SCOPE_AGENT);
        }
        s_run = run;
    }
    __syncthreads();
    const int off = s_run + locincl - val;
    if (i < N_NODES) {
        rowptr[i] = off;
        cursor[i] = off;
    }
    if (bid == 0 && threadIdx.x == 0) rowptr[N_NODES] = E_EDGES;
}

__global__ __launch_bounds__(256)
void scatter_edges(const int* __restrict__ src, const int* __restrict__ dst,
                   int* __restrict__ cursor, int* __restrict__ ssrc, int E)
{
    int i = blockIdx.x * blockDim.x + threadIdx.x;
    if (i < E) {
        int pos = atomicAdd(&cursor[dst[i]], 1);
        ssrc[pos] = src[i];
    }
}

// ---------------------------------------------------------------------------
// Layer-1 aggregation (H=4, C=64). One wave per dst node; lane owns 4 ch
// (head = lane>>4). 4-edge unroll; packed-fp16 score math + fdot2.
// (R11 shape — measured best.)
// ---------------------------------------------------------------------------
__global__ __launch_bounds__(256)
void agg1(const __half* __restrict__ xlr, const int* __restrict__ rowptr,
          const int* __restrict__ ssrc, const float* __restrict__ att,
          const float* __restrict__ b, __half* __restrict__ h)
{
    const int w = (blockIdx.x * blockDim.x + threadIdx.x) >> 6;
    if (w >= N_NODES) return;
    const int lane = threadIdx.x & 63;
    const int ch = lane * 4;

    const float4 atf = *(const float4*)(att + ch);
    const h2f at0 = cvt_h2(atf.x, atf.y);
    const h2f at1 = cvt_h2(atf.z, atf.w);
    const float4 bb = *(const float4*)(b + ch);
    union { uint2 u; h2f v[2]; } R;
    R.u = *(const uint2*)(xlr + (size_t)w * 512 + 256 + ch);
    const h2f r0 = R.v[0], r1 = R.v[1];

    float4 a = make_float4(0.f, 0.f, 0.f, 0.f);
    float den = 0.f;

    const int beg = rowptr[w], end = rowptr[w + 1];
    int i = beg;
    while (i + 4 <= end) {
        union { uint2 u; h2f v[2]; } U[4];
        #pragma unroll
        for (int j = 0; j < 4; ++j) {
            const int s = ssrc[i + j];
            U[j].u = *(const uint2*)(xlr + (size_t)s * 512 + ch);
        }
        float m[4];
        #pragma unroll
        for (int j = 0; j < 4; ++j) {
            m[j] = dot2acc(leaky2(U[j].v[0] + r0), at0, 0.f);
            m[j] = dot2acc(leaky2(U[j].v[1] + r1), at1, m[j]);
        }
        #pragma unroll
        for (int off = 1; off < 16; off <<= 1)
            #pragma unroll
            for (int j = 0; j < 4; ++j)
                m[j] += __shfl_xor(m[j], off, 64);
        #pragma unroll
        for (int j = 0; j < 4; ++j) {
            const float e = __expf(m[j]);
            a.x += e * (float)U[j].v[0][0];
            a.y += e * (float)U[j].v[0][1];
            a.z += e * (float)U[j].v[1][0];
            a.w += e * (float)U[j].v[1][1];
            den += e;
        }
        i += 4;
    }
    while (i < end) {
        const int s = ssrc[i];
        union { uint2 u; h2f v[2]; } U;
        U.u = *(const uint2*)(xlr + (size_t)s * 512 + ch);
        float m = dot2acc(leaky2(U.v[0] + r0), at0, 0.f);
        m = dot2acc(leaky2(U.v[1] + r1), at1, m);
        m += __shfl_xor(m, 1, 64);
        m += __shfl_xor(m, 2, 64);
        m += __shfl_xor(m, 4, 64);
        m += __shfl_xor(m, 8, 64);
        const float e = __expf(m);
        a.x += e * (float)U.v[0][0];
        a.y += e * (float)U.v[0][1];
        a.z += e * (float)U.v[1][0];
        a.w += e * (float)U.v[1][1];
        den += e;
        ++i;
    }

    const float inv = 1.f / (den + EPS);
    float v0 = a.x * inv + bb.x;
    float v1 = a.y * inv + bb.y;
    float v2 = a.z * inv + bb.z;
    float v3 = a.w * inv + bb.w;
    v0 = v0 > 0.f ? v0 : __expf(v0) - 1.f;
    v1 = v1 > 0.f ? v1 : __expf(v1) - 1.f;
    v2 = v2 > 0.f ? v2 : __expf(v2) - 1.f;
    v3 = v3 > 0.f ? v3 : __expf(v3) - 1.f;
    union { uint2 u; __half2 h2[2]; } O;
    O.h2[0] = __floats2half2_rn(v0, v1);
    O.h2[1] = __floats2half2_rn(v2, v3);
    *(uint2*)(h + (size_t)w * 256 + ch) = O.u;
}

// ---------------------------------------------------------------------------
// Layer-2 aggregation (H=1, C=128). Two 32-lane halves, 2-edge unroll per
// half; packed-fp16 score math as agg1. (R11 shape.)
// ---------------------------------------------------------------------------
__global__ __launch_bounds__(256)
void agg2(const __half* __restrict__ xlr, const int* __restrict__ rowptr,
          const int* __restrict__ ssrc, const float* __restrict__ att,
          const float* __restrict__ b, float* __restrict__ out)
{
    const int w = (blockIdx.x * blockDim.x + threadIdx.x) >> 6;
    if (w >= N_NODES) return;
    const int lane = threadIdx.x & 63;
    const int half = lane >> 5;
    const int ch = (lane & 31) * 4;

    const float4 atf = *(const float4*)(att + ch);
    const h2f at0 = cvt_h2(atf.x, atf.y);
    const h2f at1 = cvt_h2(atf.z, atf.w);
    const float4 bb = *(const float4*)(b + ch);
    union { uint2 u; h2f v[2]; } R;
    R.u = *(const uint2*)(xlr + (size_t)w * 256 + 128 + ch);
    const h2f r0 = R.v[0], r1 = R.v[1];

    float4 a = make_float4(0.f, 0.f, 0.f, 0.f);
    float den = 0.f;

    const int beg = rowptr[w], end = rowptr[w + 1];
    int i = beg + half;
    while (i + 2 < end) {
        union { uint2 u; h2f v[2]; } U[2];
        #pragma unroll
        for (int j = 0; j < 2; ++j) {
            const int s = ssrc[i + 2 * j];
            U[j].u = *(const uint2*)(xlr + (size_t)s * 256 + ch);
        }
        float m[2];
        #pragma unroll
        for (int j = 0; j < 2; ++j) {
            m[j] = dot2acc(leaky2(U[j].v[0] + r0), at0, 0.f);
            m[j] = dot2acc(leaky2(U[j].v[1] + r1), at1, m[j]);
        }
        #pragma unroll
        for (int off = 1; off < 32; off <<= 1)
            #pragma unroll
            for (int j = 0; j < 2; ++j)
                m[j] += __shfl_xor(m[j], off, 64);
        #pragma unroll
        for (int j = 0; j < 2; ++j) {
            const float e = __expf(m[j]);
            a.x += e * (float)U[j].v[0][0];
            a.y += e * (float)U[j].v[0][1];
            a.z += e * (float)U[j].v[1][0];
            a.w += e * (float)U[j].v[1][1];
            den += e;
        }
        i += 4;
    }
    if (i < end) {
        const int s = ssrc[i];
        union { uint2 u; h2f v[2]; } U;
        U.u = *(const uint2*)(xlr + (size_t)s * 256 + ch);
        float m = dot2acc(leaky2(U.v[0] + r0), at0, 0.f);
        m = dot2acc(leaky2(U.v[1] + r1), at1, m);
        #pragma unroll
        for (int off = 1; off < 32; off <<= 1)
            m += __shfl_xor(m, off, 64);
        const float e = __expf(m);
        a.x += e * (float)U.v[0][0];
        a.y += e * (float)U.v[0][1];
        a.z += e * (float)U.v[1][0];
        a.w += e * (float)U.v[1][1];
        den += e;
    }

    a.x += __shfl_xor(a.x, 32, 64);
    a.y += __shfl_xor(a.y, 32, 64);
    a.z += __shfl_xor(a.z, 32, 64);
    a.w += __shfl_xor(a.w, 32, 64);
    den += __shfl_xor(den, 32, 64);

    if (half == 0) {
        const float inv = 1.f / (den + EPS);
        float4 o;
        o.x = a.x * inv + bb.x;
        o.y = a.y * inv + bb.y;
        o.z = a.z * inv + bb.z;
        o.w = a.w * inv + bb.w;
        *(float4*)(out + (size_t)w * 128 + ch) = o;
    }
}

extern "C" void kernel_launch(void* const* d_in, const int* in_sizes, int n_in,
                              void* d_out, int out_size, void* d_ws, size_t ws_size,
                              hipStream_t stream)
{
    const float* x    = (const float*)d_in[0];
    const int*   ei   = (const int*)d_in[1];
    const float* Wl1  = (const float*)d_in[2];
    const float* Wr1  = (const float*)d_in[3];
    const float* att1 = (const float*)d_in[4];
    const float* b1   = (const float*)d_in[5];
    const float* Wl2  = (const float*)d_in[6];
    const float* Wr2  = (const float*)d_in[7];
    const float* att2 = (const float*)d_in[8];
    const float* b2   = (const float*)d_in[9];
    const int* src = ei;
    const int* dst = ei + E_EDGES;
    float* out = (float*)d_out;

    // Workspace layout (fp16 unless noted):
    //   xlr1 [N,512] = [xl1|xr1]   (51.2 MB); reused as xlr2 [N,256]
    //   hh   [N,256]
    //   W1t  [512,128], W2t [256,256]
    //   ints: rowptr[N+1], cursor[N], deg[N], ticket[1], state[NB_SCAN] (ull),
    //         ssrc[E].   deg..state covered by ONE memset (zero init).
    __half* xlr1 = (__half*)d_ws;
    __half* hh   = xlr1 + (size_t)N_NODES * 512;
    __half* W1t  = hh + (size_t)N_NODES * 256;
    __half* W2t  = W1t + 512 * 128;
    int* rowptr   = (int*)(W2t + 256 * 256);
    int* cursor   = rowptr + (N_NODES + 1);
    int* deg      = cursor + N_NODES;
    int* ticket   = deg + N_NODES;
    unsigned long long* state = (unsigned long long*)(ticket + 1);
    int* ssrc     = (int*)(state + NB_SCAN);
    __half* xlr2 = xlr1;

    const dim3 blk(256);
    const int hist_blocks = (E_EDGES + 255) / 256;

    // --- zero deg + ticket + lookback state in one memset ---
    hipMemsetAsync(deg, 0, (size_t)N_NODES * 4 + 4 + (size_t)NB_SCAN * 8, stream);

    // --- weight convert + dst histogram (fused, footprint-homogeneous) ---
    cvt_and_hist<<<CVT_BLOCKS + hist_blocks, blk, 0, stream>>>(
        Wl1, Wr1, Wl2, Wr2, W1t, W2t, dst, deg);

    // --- single-pass scan (decoupled lookback) ---
    scan_onepass<<<NB_SCAN, blk, 0, stream>>>(deg, state, ticket, rowptr, cursor);

    // --- edge scatter (own dispatch: needs high occupancy) ---
    scatter_edges<<<hist_blocks, blk, 0, stream>>>(src, dst, cursor, ssrc, E_EDGES);

    // --- Layer 1: [N,128] @ [128,512] (fused Wl|Wr), 128x256 tiles, BK=32 ---
    gemm_mfma<float><<<dim3(GX1, 2), blk, 0, stream>>>(x, W1t, xlr1, N_NODES, 128, 512);
    agg1<<<(N_NODES * 64 + 255) / 256, blk, 0, stream>>>(xlr1, rowptr, ssrc, att1, b1, hh);

    // --- Layer 2: [N,256] @ [256,256] (fused Wl|Wr), 128x256 tiles, BK=32 ---
    gemm_mfma<_Float16><<<dim3(GX1, 1), blk, 0, stream>>>((const _Float16*)hh, W2t, xlr2, N_NODES, 256, 256);
    agg2<<<(N_NODES * 64 + 255) / 256, blk, 0, stream>>>(xlr2, rowptr, ssrc, att2, b2, out);
}

// Round 15
// 334.426 us; speedup vs baseline: 1.1156x; 1.1156x over previous
//
#include <hip/hip_runtime.h>
#include <hip/hip_bf16.h>
#include <hip/hip_fp16.h>
#include <math.h>

#define N_NODES 50000
#define E_EDGES 800000
#define NEG_SLOPE 0.2f
#define EPS 1e-16f
#define NB_SCAN ((N_NODES + 255) / 256)   // 196
#define GX1 ((N_NODES + 127) / 128)       // 391

typedef _Float16 f16x8 __attribute__((ext_vector_type(8)));
typedef _Float16 h2f   __attribute__((ext_vector_type(2)));
typedef float    f32x4 __attribute__((ext_vector_type(4)));

// fp32 dot-accumulate of an fp16 pair product: v_dot2_f32_f16 where available
__device__ __forceinline__ float dot2acc(h2f a, h2f b, float c) {
#if __has_builtin(__builtin_amdgcn_fdot2)
    return __builtin_amdgcn_fdot2(a, b, c, false);
#else
    return c + (float)a[0] * (float)b[0] + (float)a[1] * (float)b[1];
#endif
}

// packed leaky-relu: max(s, 0.2*s) elementwise (v_pk_mul + v_pk_max)
__device__ __forceinline__ h2f leaky2(h2f s) {
    h2f t = s * (_Float16)NEG_SLOPE;
    return __builtin_elementwise_max(s, t);
}

__device__ __forceinline__ h2f cvt_h2(float x, float y) {
    h2f r; r[0] = (_Float16)x; r[1] = (_Float16)y; return r;
}

// load 8 contiguous elements as f16x8, converting if input is fp32
__device__ __forceinline__ f16x8 load8(const float* p) {
    const float4 v0 = *(const float4*)p;
    const float4 v1 = *(const float4*)(p + 4);
    f16x8 r;
    r[0] = (_Float16)v0.x; r[1] = (_Float16)v0.y;
    r[2] = (_Float16)v0.z; r[3] = (_Float16)v0.w;
    r[4] = (_Float16)v1.x; r[5] = (_Float16)v1.y;
    r[6] = (_Float16)v1.z; r[7] = (_Float16)v1.w;
    return r;
}
__device__ __forceinline__ f16x8 load8(const _Float16* p) {
    return *(const f16x8*)p;
}

// ---------------------------------------------------------------------------
// MFMA GEMM (fp16 compute, fp32 accum): Y[N, M2] = X[N,K] @ Wt[M2,K]^T,
// fp16 output. X fp32 (converted during staging) or fp16, templated.
// 128x256 tile, BK=32 (R11 best), 4 waves (2x2 over 64x128), 4x8 MFMA/wave.
// ---------------------------------------------------------------------------
template <typename IT>
__global__ __launch_bounds__(256, 2)
void gemm_mfma(const IT* __restrict__ X, const __half* __restrict__ Wth,
               __half* __restrict__ Y, int Nrows, int K, int M2)
{
    const _Float16* Wt = (const _Float16*)Wth;
    __shared__ _Float16 As[128][40];
    __shared__ _Float16 Bs[256][40];
    const int tid  = threadIdx.x;
    const int row0 = blockIdx.x * 128;
    const int col0 = blockIdx.y * 256;
    const int lane = tid & 63;
    const int wv   = tid >> 6;
    const int wr   = (wv >> 1) * 64;
    const int wc   = (wv & 1) * 128;
    const int fm   = lane & 15;
    const int fk   = (lane >> 4) * 8;
    const int quad = lane >> 4;

    f32x4 acc[4][8] = {};

    for (int k0 = 0; k0 < K; k0 += 32) {
        #pragma unroll
        for (int p = 0; p < 2; ++p) {
            const int idx = tid + p * 256;
            const int r = idx >> 2;
            const int c = (idx & 3) * 8;
            const int gr = row0 + r;
            f16x8 v = {};
            if (gr < Nrows)
                v = load8(X + (size_t)gr * K + k0 + c);
            *(f16x8*)&As[r][c] = v;
        }
        #pragma unroll
        for (int p = 0; p < 4; ++p) {
            const int idx = tid + p * 256;
            const int r = idx >> 2;
            const int c = (idx & 3) * 8;
            *(f16x8*)&Bs[r][c] = *(const f16x8*)(Wt + (size_t)(col0 + r) * K + k0 + c);
        }
        __syncthreads();

        f16x8 bf[8];
        #pragma unroll
        for (int j = 0; j < 8; ++j)
            bf[j] = *(const f16x8*)&Bs[wc + j * 16 + fm][fk];
        #pragma unroll
        for (int i = 0; i < 4; ++i) {
            const f16x8 af = *(const f16x8*)&As[wr + i * 16 + fm][fk];
            #pragma unroll
            for (int j = 0; j < 8; ++j)
                acc[i][j] = __builtin_amdgcn_mfma_f32_16x16x32_f16(af, bf[j], acc[i][j], 0, 0, 0);
        }
        __syncthreads();
    }

    #pragma unroll
    for (int i = 0; i < 4; ++i) {
        #pragma unroll
        for (int j = 0; j < 8; ++j) {
            const int col = col0 + wc + j * 16 + fm;
            #pragma unroll
            for (int rg = 0; rg < 4; ++rg) {
                const int row = row0 + wr + i * 16 + quad * 4 + rg;
                if (row < Nrows)
                    Y[(size_t)row * M2 + col] = __float2half(acc[i][j][rg]);
            }
        }
    }
}

// ---------------------------------------------------------------------------
// Fused: weight-pair fp16 transpose convert (blocks 0..511) + dst histogram
// (remaining blocks). deg must be zeroed beforehand (same-stream memset).
// ---------------------------------------------------------------------------
#define CVT_BLOCKS 512   // (512*128 + 256*256) / 256
__global__ __launch_bounds__(256)
void cvt_and_hist(const float* __restrict__ Wl1, const float* __restrict__ Wr1,
                  const float* __restrict__ Wl2, const float* __restrict__ Wr2,
                  __half* __restrict__ W1t, __half* __restrict__ W2t,
                  const int* __restrict__ dst, int* __restrict__ deg)
{
    const int b = blockIdx.x;
    if (b < CVT_BLOCKS) {
        int id = b * 256 + threadIdx.x;
        if (id < 512 * 128) {
            const int n = id >> 7, k = id & 127;          // K=128, M=256
            const float* W = (n < 256) ? Wl1 : Wr1;
            const int nn = (n < 256) ? n : n - 256;
            W1t[id] = __float2half(W[(size_t)k * 256 + nn]);
        } else {
            id -= 512 * 128;
            const int n = id >> 8, k = id & 255;          // K=256, M=128
            const float* W = (n < 128) ? Wl2 : Wr2;
            const int nn = (n < 128) ? n : n - 128;
            W2t[id] = __float2half(W[(size_t)k * 128 + nn]);
        }
    } else {
        const int i = (b - CVT_BLOCKS) * 256 + threadIdx.x;
        if (i < E_EDGES) atomicAdd(&deg[dst[i]], 1);
    }
}

// ---------------------------------------------------------------------------
// Two-phase parallel scan (R11 proven shape; the decoupled-lookback
// single-pass variant REGRESSED ~37 us -- serial cross-block spin).
// ---------------------------------------------------------------------------
__global__ __launch_bounds__(256)
void scan_local(const int* __restrict__ deg, int* __restrict__ locpre,
                int* __restrict__ blockSum)
{
    const int i = blockIdx.x * 256 + threadIdx.x;
    const int lane = threadIdx.x & 63;
    const int wid = threadIdx.x >> 6;
    const int val = (i < N_NODES) ? deg[i] : 0;

    int v = val;
    #pragma unroll
    for (int off = 1; off < 64; off <<= 1) {
        int t = __shfl_up(v, off, 64);
        if (lane >= off) v += t;
    }
    __shared__ int ws[4];
    if (lane == 63) ws[wid] = v;
    __syncthreads();
    int woff = 0;
    for (int k = 0; k < wid; ++k) woff += ws[k];
    if (i < N_NODES) locpre[i] = woff + v - val;
    if (threadIdx.x == 255) blockSum[blockIdx.x] = woff + v;
}

__global__ __launch_bounds__(256)
void scan_final(const int* __restrict__ locpre, const int* __restrict__ blockSum,
                int* __restrict__ rowptr, int* __restrict__ cursor)
{
    const int b = blockIdx.x;
    const int t = threadIdx.x;
    int v = (t < b) ? blockSum[t] : 0;          // NB_SCAN(=196) < 256
    #pragma unroll
    for (int off = 32; off; off >>= 1) v += __shfl_xor(v, off, 64);
    __shared__ int ws[4];
    if ((t & 63) == 0) ws[t >> 6] = v;
    __syncthreads();
    const int offset = ws[0] + ws[1] + ws[2] + ws[3];

    const int i = b * 256 + t;
    if (i < N_NODES) {
        const int rp = locpre[i] + offset;
        rowptr[i] = rp;
        cursor[i] = rp;
    }
    if (b == 0 && t == 0) rowptr[N_NODES] = E_EDGES;
}

__global__ __launch_bounds__(256)
void scatter_edges(const int* __restrict__ src, const int* __restrict__ dst,
                   int* __restrict__ cursor, int* __restrict__ ssrc, int E)
{
    int i = blockIdx.x * blockDim.x + threadIdx.x;
    if (i < E) {
        int pos = atomicAdd(&cursor[dst[i]], 1);
        ssrc[pos] = src[i];
    }
}

// ---------------------------------------------------------------------------
// Layer-1 aggregation (H=4, C=64). One wave per dst node; lane owns 4 ch
// (head = lane>>4). 4-edge groups, SOFTWARE-PIPELINED: group g+1's gathers
// issue before group g's compute (register double-buffer) to hide L2/L3
// gather latency. Packed-fp16 score math + fdot2 (R11 shape).
// ---------------------------------------------------------------------------
__global__ __launch_bounds__(256)
void agg1(const __half* __restrict__ xlr, const int* __restrict__ rowptr,
          const int* __restrict__ ssrc, const float* __restrict__ att,
          const float* __restrict__ b, __half* __restrict__ h)
{
    const int w = (blockIdx.x * blockDim.x + threadIdx.x) >> 6;
    if (w >= N_NODES) return;
    const int lane = threadIdx.x & 63;
    const int ch = lane * 4;

    const float4 atf = *(const float4*)(att + ch);
    const h2f at0 = cvt_h2(atf.x, atf.y);
    const h2f at1 = cvt_h2(atf.z, atf.w);
    const float4 bb = *(const float4*)(b + ch);
    union UU { uint2 u; h2f v[2]; };
    UU R;
    R.u = *(const uint2*)(xlr + (size_t)w * 512 + 256 + ch);
    const h2f r0 = R.v[0], r1 = R.v[1];

    float4 a = make_float4(0.f, 0.f, 0.f, 0.f);
    float den = 0.f;

    const int beg = rowptr[w], end = rowptr[w + 1];
    const int nfull = (end - beg) >> 2;
    int i = beg;

    UU cur[4];
    if (nfull > 0) {
        #pragma unroll
        for (int j = 0; j < 4; ++j)
            cur[j].u = *(const uint2*)(xlr + (size_t)ssrc[i + j] * 512 + ch);
    }
    for (int g = 0; g < nfull; ++g) {
        UU nxt[4];
        if (g + 1 < nfull) {                      // wave-uniform branch
            const int ib = i + 4;
            #pragma unroll
            for (int j = 0; j < 4; ++j)
                nxt[j].u = *(const uint2*)(xlr + (size_t)ssrc[ib + j] * 512 + ch);
        }
        float m[4];
        #pragma unroll
        for (int j = 0; j < 4; ++j) {
            m[j] = dot2acc(leaky2(cur[j].v[0] + r0), at0, 0.f);
            m[j] = dot2acc(leaky2(cur[j].v[1] + r1), at1, m[j]);
        }
        #pragma unroll
        for (int off = 1; off < 16; off <<= 1)
            #pragma unroll
            for (int j = 0; j < 4; ++j)
                m[j] += __shfl_xor(m[j], off, 64);
        #pragma unroll
        for (int j = 0; j < 4; ++j) {
            const float e = __expf(m[j]);
            a.x += e * (float)cur[j].v[0][0];
            a.y += e * (float)cur[j].v[0][1];
            a.z += e * (float)cur[j].v[1][0];
            a.w += e * (float)cur[j].v[1][1];
            den += e;
        }
        #pragma unroll
        for (int j = 0; j < 4; ++j) cur[j] = nxt[j];
        i += 4;
    }
    while (i < end) {
        const int s = ssrc[i];
        UU U;
        U.u = *(const uint2*)(xlr + (size_t)s * 512 + ch);
        float m = dot2acc(leaky2(U.v[0] + r0), at0, 0.f);
        m = dot2acc(leaky2(U.v[1] + r1), at1, m);
        m += __shfl_xor(m, 1, 64);
        m += __shfl_xor(m, 2, 64);
        m += __shfl_xor(m, 4, 64);
        m += __shfl_xor(m, 8, 64);
        const float e = __expf(m);
        a.x += e * (float)U.v[0][0];
        a.y += e * (float)U.v[0][1];
        a.z += e * (float)U.v[1][0];
        a.w += e * (float)U.v[1][1];
        den += e;
        ++i;
    }

    const float inv = 1.f / (den + EPS);
    float v0 = a.x * inv + bb.x;
    float v1 = a.y * inv + bb.y;
    float v2 = a.z * inv + bb.z;
    float v3 = a.w * inv + bb.w;
    v0 = v0 > 0.f ? v0 : __expf(v0) - 1.f;
    v1 = v1 > 0.f ? v1 : __expf(v1) - 1.f;
    v2 = v2 > 0.f ? v2 : __expf(v2) - 1.f;
    v3 = v3 > 0.f ? v3 : __expf(v3) - 1.f;
    union { uint2 u; __half2 h2[2]; } O;
    O.h2[0] = __floats2half2_rn(v0, v1);
    O.h2[1] = __floats2half2_rn(v2, v3);
    *(uint2*)(h + (size_t)w * 256 + ch) = O.u;
}

// ---------------------------------------------------------------------------
// Layer-2 aggregation (H=1, C=128). Two 32-lane halves, 2-edge groups per
// half, SOFTWARE-PIPELINED like agg1. Packed-fp16 score math (R11 shape).
// ---------------------------------------------------------------------------
__global__ __launch_bounds__(256)
void agg2(const __half* __restrict__ xlr, const int* __restrict__ rowptr,
          const int* __restrict__ ssrc, const float* __restrict__ att,
          const float* __restrict__ b, float* __restrict__ out)
{
    const int w = (blockIdx.x * blockDim.x + threadIdx.x) >> 6;
    if (w >= N_NODES) return;
    const int lane = threadIdx.x & 63;
    const int half = lane >> 5;
    const int ch = (lane & 31) * 4;

    const float4 atf = *(const float4*)(att + ch);
    const h2f at0 = cvt_h2(atf.x, atf.y);
    const h2f at1 = cvt_h2(atf.z, atf.w);
    const float4 bb = *(const float4*)(b + ch);
    union UU { uint2 u; h2f v[2]; };
    UU R;
    R.u = *(const uint2*)(xlr + (size_t)w * 256 + 128 + ch);
    const h2f r0 = R.v[0], r1 = R.v[1];

    float4 a = make_float4(0.f, 0.f, 0.f, 0.f);
    float den = 0.f;

    const int beg = rowptr[w], end = rowptr[w + 1];
    int i = beg + half;
    bool have = (i + 2 < end);
    UU cur[2];
    if (have) {
        cur[0].u = *(const uint2*)(xlr + (size_t)ssrc[i] * 256 + ch);
        cur[1].u = *(const uint2*)(xlr + (size_t)ssrc[i + 2] * 256 + ch);
    }
    while (have) {
        const int inext = i + 4;
        const bool havenext = (inext + 2 < end);   // wave-uniform
        UU nxt[2];
        if (havenext) {
            nxt[0].u = *(const uint2*)(xlr + (size_t)ssrc[inext] * 256 + ch);
            nxt[1].u = *(const uint2*)(xlr + (size_t)ssrc[inext + 2] * 256 + ch);
        }
        float m[2];
        #pragma unroll
        for (int j = 0; j < 2; ++j) {
            m[j] = dot2acc(leaky2(cur[j].v[0] + r0), at0, 0.f);
            m[j] = dot2acc(leaky2(cur[j].v[1] + r1), at1, m[j]);
        }
        #pragma unroll
        for (int off = 1; off < 32; off <<= 1)
            #pragma unroll
            for (int j = 0; j < 2; ++j)
                m[j] += __shfl_xor(m[j], off, 64);
        #pragma unroll
        for (int j = 0; j < 2; ++j) {
            const float e = __expf(m[j]);
            a.x += e * (float)cur[j].v[0][0];
            a.y += e * (float)cur[j].v[0][1];
            a.z += e * (float)cur[j].v[1][0];
            a.w += e * (float)cur[j].v[1][1];
            den += e;
        }
        cur[0] = nxt[0];
        cur[1] = nxt[1];
        i = inext;
        have = havenext;
    }
    if (i < end) {
        const int s = ssrc[i];
        UU U;
        U.u = *(const uint2*)(xlr + (size_t)s * 256 + ch);
        float m = dot2acc(leaky2(U.v[0] + r0), at0, 0.f);
        m = dot2acc(leaky2(U.v[1] + r1), at1, m);
        #pragma unroll
        for (int off = 1; off < 32; off <<= 1)
            m += __shfl_xor(m, off, 64);
        const float e = __expf(m);
        a.x += e * (float)U.v[0][0];
        a.y += e * (float)U.v[0][1];
        a.z += e * (float)U.v[1][0];
        a.w += e * (float)U.v[1][1];
        den += e;
    }

    a.x += __shfl_xor(a.x, 32, 64);
    a.y += __shfl_xor(a.y, 32, 64);
    a.z += __shfl_xor(a.z, 32, 64);
    a.w += __shfl_xor(a.w, 32, 64);
    den += __shfl_xor(den, 32, 64);

    if (half == 0) {
        const float inv = 1.f / (den + EPS);
        float4 o;
        o.x = a.x * inv + bb.x;
        o.y = a.y * inv + bb.y;
        o.z = a.z * inv + bb.z;
        o.w = a.w * inv + bb.w;
        *(float4*)(out + (size_t)w * 128 + ch) = o;
    }
}

extern "C" void kernel_launch(void* const* d_in, const int* in_sizes, int n_in,
                              void* d_out, int out_size, void* d_ws, size_t ws_size,
                              hipStream_t stream)
{
    const float* x    = (const float*)d_in[0];
    const int*   ei   = (const int*)d_in[1];
    const float* Wl1  = (const float*)d_in[2];
    const float* Wr1  = (const float*)d_in[3];
    const float* att1 = (const float*)d_in[4];
    const float* b1   = (const float*)d_in[5];
    const float* Wl2  = (const float*)d_in[6];
    const float* Wr2  = (const float*)d_in[7];
    const float* att2 = (const float*)d_in[8];
    const float* b2   = (const float*)d_in[9];
    const int* src = ei;
    const int* dst = ei + E_EDGES;
    float* out = (float*)d_out;

    // Workspace layout (fp16 unless noted):
    //   xlr1 [N,512] = [xl1|xr1]   (51.2 MB); reused as xlr2 [N,256]
    //   hh   [N,256]
    //   W1t  [512,128], W2t [256,256]
    //   ints: rowptr[N+1], cursor[N], deg[N], ssrc[E], locpre[N], blockSum[NB]
    __half* xlr1 = (__half*)d_ws;
    __half* hh   = xlr1 + (size_t)N_NODES * 512;
    __half* W1t  = hh + (size_t)N_NODES * 256;
    __half* W2t  = W1t + 512 * 128;
    int* rowptr   = (int*)(W2t + 256 * 256);
    int* cursor   = rowptr + (N_NODES + 1);
    int* deg      = cursor + N_NODES;
    int* ssrc     = deg + N_NODES;
    int* locpre   = ssrc + E_EDGES;
    int* blockSum = locpre + N_NODES;
    __half* xlr2 = xlr1;

    const dim3 blk(256);
    const int hist_blocks = (E_EDGES + 255) / 256;

    // --- zero deg ---
    hipMemsetAsync(deg, 0, (size_t)N_NODES * 4, stream);

    // --- weight convert + dst histogram (fused, footprint-homogeneous) ---
    cvt_and_hist<<<CVT_BLOCKS + hist_blocks, blk, 0, stream>>>(
        Wl1, Wr1, Wl2, Wr2, W1t, W2t, dst, deg);

    // --- two-phase scan (R11 proven) ---
    scan_local<<<NB_SCAN, blk, 0, stream>>>(deg, locpre, blockSum);
    scan_final<<<NB_SCAN, blk, 0, stream>>>(locpre, blockSum, rowptr, cursor);

    // --- edge scatter ---
    scatter_edges<<<hist_blocks, blk, 0, stream>>>(src, dst, cursor, ssrc, E_EDGES);

    // --- Layer 1: [N,128] @ [128,512] (fused Wl|Wr), 128x256 tiles, BK=32 ---
    gemm_mfma<float><<<dim3(GX1, 2), blk, 0, stream>>>(x, W1t, xlr1, N_NODES, 128, 512);
    agg1<<<(N_NODES * 64 + 255) / 256, blk, 0, stream>>>(xlr1, rowptr, ssrc, att1, b1, hh);

    // --- Layer 2: [N,256] @ [256,256] (fused Wl|Wr), 128x256 tiles, BK=32 ---
    gemm_mfma<_Float16><<<dim3(GX1, 1), blk, 0, stream>>>((const _Float16*)hh, W2t, xlr2, N_NODES, 256, 256);
    agg2<<<(N_NODES * 64 + 255) / 256, blk, 0, stream>>>(xlr2, rowptr, ssrc, att2, b2, out);
}

// Round 16
// 332.362 us; speedup vs baseline: 1.1225x; 1.0062x over previous
//
#include <hip/hip_runtime.h>
#include <hip/hip_bf16.h>
#include <hip/hip_fp16.h>
#include <math.h>

#define N_NODES 50000
#define E_EDGES 800000
#define NEG_SLOPE 0.2f
#define EPS 1e-16f
#define NB_SCAN ((N_NODES + 255) / 256)   // 196
#define GX1 ((N_NODES + 127) / 128)       // 391

typedef _Float16 f16x8 __attribute__((ext_vector_type(8)));
typedef _Float16 h2f   __attribute__((ext_vector_type(2)));
typedef float    f32x4 __attribute__((ext_vector_type(4)));

// fp32 dot-accumulate of an fp16 pair product: v_dot2_f32_f16 where available
__device__ __forceinline__ float dot2acc(h2f a, h2f b, float c) {
#if __has_builtin(__builtin_amdgcn_fdot2)
    return __builtin_amdgcn_fdot2(a, b, c, false);
#else
    return c + (float)a[0] * (float)b[0] + (float)a[1] * (float)b[1];
#endif
}

// packed leaky-relu: max(s, 0.2*s) elementwise (v_pk_mul + v_pk_max)
__device__ __forceinline__ h2f leaky2(h2f s) {
    h2f t = s * (_Float16)NEG_SLOPE;
    return __builtin_elementwise_max(s, t);
}

__device__ __forceinline__ h2f cvt_h2(float x, float y) {
    h2f r; r[0] = (_Float16)x; r[1] = (_Float16)y; return r;
}

// load 8 contiguous elements as f16x8, converting if input is fp32
__device__ __forceinline__ f16x8 load8(const float* p) {
    const float4 v0 = *(const float4*)p;
    const float4 v1 = *(const float4*)(p + 4);
    f16x8 r;
    r[0] = (_Float16)v0.x; r[1] = (_Float16)v0.y;
    r[2] = (_Float16)v0.z; r[3] = (_Float16)v0.w;
    r[4] = (_Float16)v1.x; r[5] = (_Float16)v1.y;
    r[6] = (_Float16)v1.z; r[7] = (_Float16)v1.w;
    return r;
}
__device__ __forceinline__ f16x8 load8(const _Float16* p) {
    return *(const f16x8*)p;
}

// ---------------------------------------------------------------------------
// MFMA GEMM (fp16 compute, fp32 accum): Y[N, M2] = X[N,K] @ Wt[M2,K]^T,
// fp16 output. X fp32 (converted during staging) or fp16, templated.
// 128x256 tile, BK=32 (R11 best; BK=64 was neutral-negative R12),
// 4 waves (2x2 over 64x128), 4x8 MFMA tiles/wave. All blocks co-resident
// (<=1280 slots) so no tail problem.
// ---------------------------------------------------------------------------
template <typename IT>
__global__ __launch_bounds__(256, 2)
void gemm_mfma(const IT* __restrict__ X, const __half* __restrict__ Wth,
               __half* __restrict__ Y, int Nrows, int K, int M2)
{
    const _Float16* Wt = (const _Float16*)Wth;
    __shared__ _Float16 As[128][40];
    __shared__ _Float16 Bs[256][40];
    const int tid  = threadIdx.x;
    const int row0 = blockIdx.x * 128;
    const int col0 = blockIdx.y * 256;
    const int lane = tid & 63;
    const int wv   = tid >> 6;
    const int wr   = (wv >> 1) * 64;
    const int wc   = (wv & 1) * 128;
    const int fm   = lane & 15;
    const int fk   = (lane >> 4) * 8;
    const int quad = lane >> 4;

    f32x4 acc[4][8] = {};

    for (int k0 = 0; k0 < K; k0 += 32) {
        #pragma unroll
        for (int p = 0; p < 2; ++p) {
            const int idx = tid + p * 256;
            const int r = idx >> 2;
            const int c = (idx & 3) * 8;
            const int gr = row0 + r;
            f16x8 v = {};
            if (gr < Nrows)
                v = load8(X + (size_t)gr * K + k0 + c);
            *(f16x8*)&As[r][c] = v;
        }
        #pragma unroll
        for (int p = 0; p < 4; ++p) {
            const int idx = tid + p * 256;
            const int r = idx >> 2;
            const int c = (idx & 3) * 8;
            *(f16x8*)&Bs[r][c] = *(const f16x8*)(Wt + (size_t)(col0 + r) * K + k0 + c);
        }
        __syncthreads();

        f16x8 bf[8];
        #pragma unroll
        for (int j = 0; j < 8; ++j)
            bf[j] = *(const f16x8*)&Bs[wc + j * 16 + fm][fk];
        #pragma unroll
        for (int i = 0; i < 4; ++i) {
            const f16x8 af = *(const f16x8*)&As[wr + i * 16 + fm][fk];
            #pragma unroll
            for (int j = 0; j < 8; ++j)
                acc[i][j] = __builtin_amdgcn_mfma_f32_16x16x32_f16(af, bf[j], acc[i][j], 0, 0, 0);
        }
        __syncthreads();
    }

    #pragma unroll
    for (int i = 0; i < 4; ++i) {
        #pragma unroll
        for (int j = 0; j < 8; ++j) {
            const int col = col0 + wc + j * 16 + fm;
            #pragma unroll
            for (int rg = 0; rg < 4; ++rg) {
                const int row = row0 + wr + i * 16 + quad * 4 + rg;
                if (row < Nrows)
                    Y[(size_t)row * M2 + col] = __float2half(acc[i][j][rg]);
            }
        }
    }
}

// ---------------------------------------------------------------------------
// Fused: weight-pair fp16 transpose convert (blocks 0..511) + dst histogram
// (remaining blocks). deg must be zeroed beforehand (same-stream memset).
// Footprint-homogeneous fusion (both tiny) — the gemm+scatter fusion (R13)
// regressed because scatter inherited gemm's 100-VGPR/30KB-LDS footprint.
// ---------------------------------------------------------------------------
#define CVT_BLOCKS 512   // (512*128 + 256*256) / 256
__global__ __launch_bounds__(256)
void cvt_and_hist(const float* __restrict__ Wl1, const float* __restrict__ Wr1,
                  const float* __restrict__ Wl2, const float* __restrict__ Wr2,
                  __half* __restrict__ W1t, __half* __restrict__ W2t,
                  const int* __restrict__ dst, int* __restrict__ deg)
{
    const int b = blockIdx.x;
    if (b < CVT_BLOCKS) {
        int id = b * 256 + threadIdx.x;
        if (id < 512 * 128) {
            const int n = id >> 7, k = id & 127;          // K=128, M=256
            const float* W = (n < 256) ? Wl1 : Wr1;
            const int nn = (n < 256) ? n : n - 256;
            W1t[id] = __float2half(W[(size_t)k * 256 + nn]);
        } else {
            id -= 512 * 128;
            const int n = id >> 8, k = id & 255;          // K=256, M=128
            const float* W = (n < 128) ? Wl2 : Wr2;
            const int nn = (n < 128) ? n : n - 128;
            W2t[id] = __float2half(W[(size_t)k * 128 + nn]);
        }
    } else {
        const int i = (b - CVT_BLOCKS) * 256 + threadIdx.x;
        if (i < E_EDGES) atomicAdd(&deg[dst[i]], 1);
    }
}

// ---------------------------------------------------------------------------
// Two-phase parallel scan (R11 proven; decoupled-lookback single-pass
// REGRESSED ~37 us via serial cross-block L2-atomic spin — R14).
// ---------------------------------------------------------------------------
__global__ __launch_bounds__(256)
void scan_local(const int* __restrict__ deg, int* __restrict__ locpre,
                int* __restrict__ blockSum)
{
    const int i = blockIdx.x * 256 + threadIdx.x;
    const int lane = threadIdx.x & 63;
    const int wid = threadIdx.x >> 6;
    const int val = (i < N_NODES) ? deg[i] : 0;

    int v = val;
    #pragma unroll
    for (int off = 1; off < 64; off <<= 1) {
        int t = __shfl_up(v, off, 64);
        if (lane >= off) v += t;
    }
    __shared__ int ws[4];
    if (lane == 63) ws[wid] = v;
    __syncthreads();
    int woff = 0;
    for (int k = 0; k < wid; ++k) woff += ws[k];
    if (i < N_NODES) locpre[i] = woff + v - val;
    if (threadIdx.x == 255) blockSum[blockIdx.x] = woff + v;
}

__global__ __launch_bounds__(256)
void scan_final(const int* __restrict__ locpre, const int* __restrict__ blockSum,
                int* __restrict__ rowptr, int* __restrict__ cursor)
{
    const int b = blockIdx.x;
    const int t = threadIdx.x;
    int v = (t < b) ? blockSum[t] : 0;          // NB_SCAN(=196) < 256
    #pragma unroll
    for (int off = 32; off; off >>= 1) v += __shfl_xor(v, off, 64);
    __shared__ int ws[4];
    if ((t & 63) == 0) ws[t >> 6] = v;
    __syncthreads();
    const int offset = ws[0] + ws[1] + ws[2] + ws[3];

    const int i = b * 256 + t;
    if (i < N_NODES) {
        const int rp = locpre[i] + offset;
        rowptr[i] = rp;
        cursor[i] = rp;
    }
    if (b == 0 && t == 0) rowptr[N_NODES] = E_EDGES;
}

__global__ __launch_bounds__(256)
void scatter_edges(const int* __restrict__ src, const int* __restrict__ dst,
                   int* __restrict__ cursor, int* __restrict__ ssrc, int E)
{
    int i = blockIdx.x * blockDim.x + threadIdx.x;
    if (i < E) {
        int pos = atomicAdd(&cursor[dst[i]], 1);
        ssrc[pos] = src[i];
    }
}

// ---------------------------------------------------------------------------
// Layer-1 aggregation (H=4, C=64) — R11 shape VERBATIM (best measured:
// 68 us; R8 wave re-partition and R15 sw-pipelining both regressed it).
// One wave per dst node; lane owns 4 ch (head = lane>>4). 4-edge unroll;
// packed-fp16 score math + fdot2; fp32 accumulate.
// ---------------------------------------------------------------------------
__global__ __launch_bounds__(256)
void agg1(const __half* __restrict__ xlr, const int* __restrict__ rowptr,
          const int* __restrict__ ssrc, const float* __restrict__ att,
          const float* __restrict__ b, __half* __restrict__ h)
{
    const int w = (blockIdx.x * blockDim.x + threadIdx.x) >> 6;
    if (w >= N_NODES) return;
    const int lane = threadIdx.x & 63;
    const int ch = lane * 4;

    const float4 atf = *(const float4*)(att + ch);
    const h2f at0 = cvt_h2(atf.x, atf.y);
    const h2f at1 = cvt_h2(atf.z, atf.w);
    const float4 bb = *(const float4*)(b + ch);
    union { uint2 u; h2f v[2]; } R;
    R.u = *(const uint2*)(xlr + (size_t)w * 512 + 256 + ch);
    const h2f r0 = R.v[0], r1 = R.v[1];

    float4 a = make_float4(0.f, 0.f, 0.f, 0.f);
    float den = 0.f;

    const int beg = rowptr[w], end = rowptr[w + 1];
    int i = beg;
    while (i + 4 <= end) {
        union { uint2 u; h2f v[2]; } U[4];
        #pragma unroll
        for (int j = 0; j < 4; ++j) {
            const int s = ssrc[i + j];
            U[j].u = *(const uint2*)(xlr + (size_t)s * 512 + ch);
        }
        float m[4];
        #pragma unroll
        for (int j = 0; j < 4; ++j) {
            m[j] = dot2acc(leaky2(U[j].v[0] + r0), at0, 0.f);
            m[j] = dot2acc(leaky2(U[j].v[1] + r1), at1, m[j]);
        }
        #pragma unroll
        for (int off = 1; off < 16; off <<= 1)
            #pragma unroll
            for (int j = 0; j < 4; ++j)
                m[j] += __shfl_xor(m[j], off, 64);
        #pragma unroll
        for (int j = 0; j < 4; ++j) {
            const float e = __expf(m[j]);
            a.x += e * (float)U[j].v[0][0];
            a.y += e * (float)U[j].v[0][1];
            a.z += e * (float)U[j].v[1][0];
            a.w += e * (float)U[j].v[1][1];
            den += e;
        }
        i += 4;
    }
    while (i < end) {
        const int s = ssrc[i];
        union { uint2 u; h2f v[2]; } U;
        U.u = *(const uint2*)(xlr + (size_t)s * 512 + ch);
        float m = dot2acc(leaky2(U.v[0] + r0), at0, 0.f);
        m = dot2acc(leaky2(U.v[1] + r1), at1, m);
        m += __shfl_xor(m, 1, 64);
        m += __shfl_xor(m, 2, 64);
        m += __shfl_xor(m, 4, 64);
        m += __shfl_xor(m, 8, 64);
        const float e = __expf(m);
        a.x += e * (float)U.v[0][0];
        a.y += e * (float)U.v[0][1];
        a.z += e * (float)U.v[1][0];
        a.w += e * (float)U.v[1][1];
        den += e;
        ++i;
    }

    const float inv = 1.f / (den + EPS);
    float v0 = a.x * inv + bb.x;
    float v1 = a.y * inv + bb.y;
    float v2 = a.z * inv + bb.z;
    float v3 = a.w * inv + bb.w;
    v0 = v0 > 0.f ? v0 : __expf(v0) - 1.f;
    v1 = v1 > 0.f ? v1 : __expf(v1) - 1.f;
    v2 = v2 > 0.f ? v2 : __expf(v2) - 1.f;
    v3 = v3 > 0.f ? v3 : __expf(v3) - 1.f;
    union { uint2 u; __half2 h2[2]; } O;
    O.h2[0] = __floats2half2_rn(v0, v1);
    O.h2[1] = __floats2half2_rn(v2, v3);
    *(uint2*)(h + (size_t)w * 256 + ch) = O.u;
}

// ---------------------------------------------------------------------------
// Layer-2 aggregation (H=1, C=128) — R11 shape VERBATIM. Two 32-lane halves,
// 2-edge unroll per half; packed-fp16 score math.
// ---------------------------------------------------------------------------
__global__ __launch_bounds__(256)
void agg2(const __half* __restrict__ xlr, const int* __restrict__ rowptr,
          const int* __restrict__ ssrc, const float* __restrict__ att,
          const float* __restrict__ b, float* __restrict__ out)
{
    const int w = (blockIdx.x * blockDim.x + threadIdx.x) >> 6;
    if (w >= N_NODES) return;
    const int lane = threadIdx.x & 63;
    const int half = lane >> 5;
    const int ch = (lane & 31) * 4;

    const float4 atf = *(const float4*)(att + ch);
    const h2f at0 = cvt_h2(atf.x, atf.y);
    const h2f at1 = cvt_h2(atf.z, atf.w);
    const float4 bb = *(const float4*)(b + ch);
    union { uint2 u; h2f v[2]; } R;
    R.u = *(const uint2*)(xlr + (size_t)w * 256 + 128 + ch);
    const h2f r0 = R.v[0], r1 = R.v[1];

    float4 a = make_float4(0.f, 0.f, 0.f, 0.f);
    float den = 0.f;

    const int beg = rowptr[w], end = rowptr[w + 1];
    int i = beg + half;
    while (i + 2 < end) {
        union { uint2 u; h2f v[2]; } U[2];
        #pragma unroll
        for (int j = 0; j < 2; ++j) {
            const int s = ssrc[i + 2 * j];
            U[j].u = *(const uint2*)(xlr + (size_t)s * 256 + ch);
        }
        float m[2];
        #pragma unroll
        for (int j = 0; j < 2; ++j) {
            m[j] = dot2acc(leaky2(U[j].v[0] + r0), at0, 0.f);
            m[j] = dot2acc(leaky2(U[j].v[1] + r1), at1, m[j]);
        }
        #pragma unroll
        for (int off = 1; off < 32; off <<= 1)
            #pragma unroll
            for (int j = 0; j < 2; ++j)
                m[j] += __shfl_xor(m[j], off, 64);
        #pragma unroll
        for (int j = 0; j < 2; ++j) {
            const float e = __expf(m[j]);
            a.x += e * (float)U[j].v[0][0];
            a.y += e * (float)U[j].v[0][1];
            a.z += e * (float)U[j].v[1][0];
            a.w += e * (float)U[j].v[1][1];
            den += e;
        }
        i += 4;
    }
    if (i < end) {
        const int s = ssrc[i];
        union { uint2 u; h2f v[2]; } U;
        U.u = *(const uint2*)(xlr + (size_t)s * 256 + ch);
        float m = dot2acc(leaky2(U.v[0] + r0), at0, 0.f);
        m = dot2acc(leaky2(U.v[1] + r1), at1, m);
        #pragma unroll
        for (int off = 1; off < 32; off <<= 1)
            m += __shfl_xor(m, off, 64);
        const float e = __expf(m);
        a.x += e * (float)U.v[0][0];
        a.y += e * (float)U.v[0][1];
        a.z += e * (float)U.v[1][0];
        a.w += e * (float)U.v[1][1];
        den += e;
    }

    a.x += __shfl_xor(a.x, 32, 64);
    a.y += __shfl_xor(a.y, 32, 64);
    a.z += __shfl_xor(a.z, 32, 64);
    a.w += __shfl_xor(a.w, 32, 64);
    den += __shfl_xor(den, 32, 64);

    if (half == 0) {
        const float inv = 1.f / (den + EPS);
        float4 o;
        o.x = a.x * inv + bb.x;
        o.y = a.y * inv + bb.y;
        o.z = a.z * inv + bb.z;
        o.w = a.w * inv + bb.w;
        *(float4*)(out + (size_t)w * 128 + ch) = o;
    }
}

extern "C" void kernel_launch(void* const* d_in, const int* in_sizes, int n_in,
                              void* d_out, int out_size, void* d_ws, size_t ws_size,
                              hipStream_t stream)
{
    const float* x    = (const float*)d_in[0];
    const int*   ei   = (const int*)d_in[1];
    const float* Wl1  = (const float*)d_in[2];
    const float* Wr1  = (const float*)d_in[3];
    const float* att1 = (const float*)d_in[4];
    const float* b1   = (const float*)d_in[5];
    const float* Wl2  = (const float*)d_in[6];
    const float* Wr2  = (const float*)d_in[7];
    const float* att2 = (const float*)d_in[8];
    const float* b2   = (const float*)d_in[9];
    const int* src = ei;
    const int* dst = ei + E_EDGES;
    float* out = (float*)d_out;

    // Workspace layout (fp16 unless noted):
    //   xlr1 [N,512] = [xl1|xr1]   (51.2 MB); reused as xlr2 [N,256]
    //   hh   [N,256]
    //   W1t  [512,128], W2t [256,256]
    //   ints: rowptr[N+1], cursor[N], deg[N], ssrc[E], locpre[N], blockSum[NB]
    __half* xlr1 = (__half*)d_ws;
    __half* hh   = xlr1 + (size_t)N_NODES * 512;
    __half* W1t  = hh + (size_t)N_NODES * 256;
    __half* W2t  = W1t + 512 * 128;
    int* rowptr   = (int*)(W2t + 256 * 256);
    int* cursor   = rowptr + (N_NODES + 1);
    int* deg      = cursor + N_NODES;
    int* ssrc     = deg + N_NODES;
    int* locpre   = ssrc + E_EDGES;
    int* blockSum = locpre + N_NODES;
    __half* xlr2 = xlr1;

    const dim3 blk(256);
    const int hist_blocks = (E_EDGES + 255) / 256;

    // --- zero deg ---
    hipMemsetAsync(deg, 0, (size_t)N_NODES * 4, stream);

    // --- weight convert + dst histogram (fused, footprint-homogeneous) ---
    cvt_and_hist<<<CVT_BLOCKS + hist_blocks, blk, 0, stream>>>(
        Wl1, Wr1, Wl2, Wr2, W1t, W2t, dst, deg);

    // --- two-phase scan (R11 proven) ---
    scan_local<<<NB_SCAN, blk, 0, stream>>>(deg, locpre, blockSum);
    scan_final<<<NB_SCAN, blk, 0, stream>>>(locpre, blockSum, rowptr, cursor);

    // --- edge scatter ---
    scatter_edges<<<hist_blocks, blk, 0, stream>>>(src, dst, cursor, ssrc, E_EDGES);

    // --- Layer 1: [N,128] @ [128,512] (fused Wl|Wr), 128x256 tiles, BK=32 ---
    gemm_mfma<float><<<dim3(GX1, 2), blk, 0, stream>>>(x, W1t, xlr1, N_NODES, 128, 512);
    agg1<<<(N_NODES * 64 + 255) / 256, blk, 0, stream>>>(xlr1, rowptr, ssrc, att1, b1, hh);

    // --- Layer 2: [N,256] @ [256,256] (fused Wl|Wr), 128x256 tiles, BK=32 ---
    gemm_mfma<_Float16><<<dim3(GX1, 1), blk, 0, stream>>>((const _Float16*)hh, W2t, xlr2, N_NODES, 256, 256);
    agg2<<<(N_NODES * 64 + 255) / 256, blk, 0, stream>>>(xlr2, rowptr, ssrc, att2, b2, out);
}